// Round 4
// baseline (25.556 us; speedup 1.0000x reference)
//
#include <hip/hip_runtime.h>

#define DDIM 256

__global__ __launch_bounds__(256) void geoprod_kernel(
    const float* __restrict__ x, const float* __restrict__ w,
    float* __restrict__ out, int n_threads)
{
    // Folded coefficient table: [0..7] diagonal (all -> k=0),
    // [8..35] upper-tri pair coeffs c(i,j)+c(j,i).
    __shared__ __align__(16) float ctab[36];
    const int tid = threadIdx.x;
    if (tid < 64) {
        const int order[8] = {0, 1, 2, 4, 3, 5, 6, 7};
        const int i = tid >> 3, j = tid & 7;
        const int a = order[i], b = order[j];
        int s = 0, t = a >> 1;
        while (t) { s += __popc(t & b); t >>= 1; }
        const float sig = 1.0f / (1.0f + expf(-w[tid]));
        const float v = (s & 1) ? -sig : sig;      // sign(i,j)*sigmoid(w[i,j])
        const float vp = __shfl(v, j * 8 + i);     // partner term (j,i)
        if (i == j)      ctab[i] = v;
        else if (i < j)  ctab[8 + (i * (15 - i)) / 2 + (j - i - 1)] = v + vp;
    }
    __syncthreads();

    const int gid = blockIdx.x * 256 + tid;
    if (gid >= n_threads) return;

    // Coefficients are wave-uniform: hoist to SGPRs via readfirstlane so the
    // FMA chain uses SGPR operands and VGPR pressure stays low (occupancy).
    float cs[36];
    #pragma unroll
    for (int q = 0; q < 36; ++q)
        cs[q] = __int_as_float(
            __builtin_amdgcn_readfirstlane(__float_as_int(ctab[q])));

    const int base = (gid >> 6) * (8 * DDIM) + (gid & 63) * 4;

    float4 xv[8];
    #pragma unroll
    for (int i = 0; i < 8; ++i)
        xv[i] = *reinterpret_cast<const float4*>(x + base + i * DDIM);

    // k = 0: the 8 diagonal terms. Store immediately (NT: write-once stream).
    {
        float4 a0 = make_float4(0.f, 0.f, 0.f, 0.f);
        #pragma unroll
        for (int i = 0; i < 8; ++i) {
            a0.x += cs[i] * xv[i].x * xv[i].x;
            a0.y += cs[i] * xv[i].y * xv[i].y;
            a0.z += cs[i] * xv[i].z * xv[i].z;
            a0.w += cs[i] * xv[i].w * xv[i].w;
        }
        float* p = out + base;
        __builtin_nontemporal_store(a0.x, p + 0);
        __builtin_nontemporal_store(a0.y, p + 1);
        __builtin_nontemporal_store(a0.z, p + 2);
        __builtin_nontemporal_store(a0.w, p + 3);
    }

    // k = 1..7: exactly 4 folded pairs each; store each quad when complete.
    static constexpr int P[7][4][2] = {
        {{0,1},{2,4},{3,5},{6,7}},   // k=1
        {{0,2},{1,4},{3,6},{5,7}},   // k=2
        {{0,3},{1,5},{2,6},{4,7}},   // k=3
        {{0,4},{1,2},{3,7},{5,6}},   // k=4
        {{0,5},{1,3},{2,7},{4,6}},   // k=5
        {{0,6},{1,7},{2,3},{4,5}},   // k=6
        {{0,7},{1,6},{2,5},{3,4}},   // k=7
    };
    #pragma unroll
    for (int kk = 0; kk < 7; ++kk) {
        float4 a = make_float4(0.f, 0.f, 0.f, 0.f);
        #pragma unroll
        for (int t2 = 0; t2 < 4; ++t2) {
            const int i = P[kk][t2][0], j = P[kk][t2][1];
            const float cc = cs[8 + (i * (15 - i)) / 2 + (j - i - 1)];
            a.x += cc * xv[i].x * xv[j].x;
            a.y += cc * xv[i].y * xv[j].y;
            a.z += cc * xv[i].z * xv[j].z;
            a.w += cc * xv[i].w * xv[j].w;
        }
        float* p = out + base + (kk + 1) * DDIM;
        __builtin_nontemporal_store(a.x, p + 0);
        __builtin_nontemporal_store(a.y, p + 1);
        __builtin_nontemporal_store(a.z, p + 2);
        __builtin_nontemporal_store(a.w, p + 3);
    }
}

extern "C" void kernel_launch(void* const* d_in, const int* in_sizes, int n_in,
                              void* d_out, int out_size, void* d_ws, size_t ws_size,
                              hipStream_t stream) {
    const float* x = (const float*)d_in[0];
    const float* w = (const float*)d_in[1];
    float* out = (float*)d_out;

    const int total = in_sizes[0];            // B*T*NB*D elements
    const int n_threads = total / 32;         // each thread: 8 blades x 4 elems
    const int blocks = (n_threads + 255) / 256;

    geoprod_kernel<<<blocks, 256, 0, stream>>>(x, w, out, n_threads);
}

// Round 5
// 25.188 us; speedup vs baseline: 1.0146x; 1.0146x over previous
//
#include <hip/hip_runtime.h>

#define DDIM 256

// Extract wave-uniform coefficient for pair (i,j) from the per-lane folded
// value vf (lane i*8+j holds c(i,j)+c(j,i); diagonal pre-halved so it works
// out to c(i,i)). Compile-time lane index -> lands in an SGPR.
#define COEF(vf, I, J) \
    __int_as_float(__builtin_amdgcn_readlane(__float_as_int(vf), (I) * 8 + (J)))

__global__ __launch_bounds__(256) void geoprod_kernel(
    const float* __restrict__ x, const float* __restrict__ w,
    float* __restrict__ out, int n_threads)
{
    const int tid = threadIdx.x;
    const int gid = blockIdx.x * 256 + tid;
    const int lane = tid & 63;

    // ---- per-wave coefficient build: no LDS, no barriers ----
    // lane l = (i,j) = (l>>3, l&7); computes sign(i,j)*sigmoid(w[i,j]).
    {
    }
    const int order[8] = {0, 1, 2, 4, 3, 5, 6, 7};
    const int li = lane >> 3, lj = lane & 7;
    const int a = order[li], b = order[lj];
    int s = 0, t = a >> 1;
    while (t) { s += __popc(t & b); t >>= 1; }
    const float sig = 1.0f / (1.0f + __expf(-w[lane]));
    float v = (s & 1) ? -sig : sig;
    if (li == lj) v *= 0.5f;                    // diagonal folds with itself
    const float vf = v + __shfl(v, lj * 8 + li); // + partner term (j,i)

    if (gid >= n_threads) return;

    const int base = (gid >> 6) * (8 * DDIM) + (gid & 63) * 4;

    float4 xv[8];
    #pragma unroll
    for (int i = 0; i < 8; ++i)
        xv[i] = *reinterpret_cast<const float4*>(x + base + i * DDIM);

    // k = 0: the 8 diagonal terms. Store immediately (NT: write-once stream).
    {
        float4 a0 = make_float4(0.f, 0.f, 0.f, 0.f);
        #pragma unroll
        for (int i = 0; i < 8; ++i) {
            const float c = COEF(vf, i, i);
            a0.x += c * xv[i].x * xv[i].x;
            a0.y += c * xv[i].y * xv[i].y;
            a0.z += c * xv[i].z * xv[i].z;
            a0.w += c * xv[i].w * xv[i].w;
        }
        float* p = out + base;
        __builtin_nontemporal_store(a0.x, p + 0);
        __builtin_nontemporal_store(a0.y, p + 1);
        __builtin_nontemporal_store(a0.z, p + 2);
        __builtin_nontemporal_store(a0.w, p + 3);
    }

    // k = 1..7: exactly 4 folded pairs each; store each quad when complete.
    static constexpr int P[7][4][2] = {
        {{0,1},{2,4},{3,5},{6,7}},   // k=1
        {{0,2},{1,4},{3,6},{5,7}},   // k=2
        {{0,3},{1,5},{2,6},{4,7}},   // k=3
        {{0,4},{1,2},{3,7},{5,6}},   // k=4
        {{0,5},{1,3},{2,7},{4,6}},   // k=5
        {{0,6},{1,7},{2,3},{4,5}},   // k=6
        {{0,7},{1,6},{2,5},{3,4}},   // k=7
    };
    #pragma unroll
    for (int kk = 0; kk < 7; ++kk) {
        float4 acc = make_float4(0.f, 0.f, 0.f, 0.f);
        #pragma unroll
        for (int t2 = 0; t2 < 4; ++t2) {
            const int i = P[kk][t2][0], j = P[kk][t2][1];
            const float cc = COEF(vf, i, j);
            acc.x += cc * xv[i].x * xv[j].x;
            acc.y += cc * xv[i].y * xv[j].y;
            acc.z += cc * xv[i].z * xv[j].z;
            acc.w += cc * xv[i].w * xv[j].w;
        }
        float* p = out + base + (kk + 1) * DDIM;
        __builtin_nontemporal_store(acc.x, p + 0);
        __builtin_nontemporal_store(acc.y, p + 1);
        __builtin_nontemporal_store(acc.z, p + 2);
        __builtin_nontemporal_store(acc.w, p + 3);
    }
}

extern "C" void kernel_launch(void* const* d_in, const int* in_sizes, int n_in,
                              void* d_out, int out_size, void* d_ws, size_t ws_size,
                              hipStream_t stream) {
    const float* x = (const float*)d_in[0];
    const float* w = (const float*)d_in[1];
    float* out = (float*)d_out;

    const int total = in_sizes[0];            // B*T*NB*D elements
    const int n_threads = total / 32;         // each thread: 8 blades x 4 elems
    const int blocks = (n_threads + 255) / 256;

    geoprod_kernel<<<blocks, 256, 0, stream>>>(x, w, out, n_threads);
}

// Round 6
// 25.122 us; speedup vs baseline: 1.0173x; 1.0026x over previous
//
#include <hip/hip_runtime.h>

#define DDIM 256

// Wave-uniform coefficient for pair (i,j): lane i*8+j of vf holds
// c(i,j)+c(j,i) (diagonal pre-halved). Compile-time lane -> SGPR.
#define COEF(vf, I, J) \
    __int_as_float(__builtin_amdgcn_readlane(__float_as_int(vf), (I) * 8 + (J)))

__device__ __forceinline__ void load_x(const float* __restrict__ x, int base,
                                       float4 xv[8]) {
    #pragma unroll
    for (int i = 0; i < 8; ++i)
        xv[i] = *reinterpret_cast<const float4*>(x + base + i * DDIM);
}

__device__ __forceinline__ void compute_store(const float4 xv[8], float vf,
                                              float* __restrict__ out, int base) {
    // k = 0: diagonal terms.
    {
        float4 a0 = make_float4(0.f, 0.f, 0.f, 0.f);
        #pragma unroll
        for (int i = 0; i < 8; ++i) {
            const float c = COEF(vf, i, i);
            a0.x += c * xv[i].x * xv[i].x;
            a0.y += c * xv[i].y * xv[i].y;
            a0.z += c * xv[i].z * xv[i].z;
            a0.w += c * xv[i].w * xv[i].w;
        }
        float* p = out + base;
        __builtin_nontemporal_store(a0.x, p + 0);
        __builtin_nontemporal_store(a0.y, p + 1);
        __builtin_nontemporal_store(a0.z, p + 2);
        __builtin_nontemporal_store(a0.w, p + 3);
    }
    // k = 1..7: 4 folded pairs each (Latin-square structure of the Cayley map).
    static constexpr int P[7][4][2] = {
        {{0,1},{2,4},{3,5},{6,7}},   // k=1
        {{0,2},{1,4},{3,6},{5,7}},   // k=2
        {{0,3},{1,5},{2,6},{4,7}},   // k=3
        {{0,4},{1,2},{3,7},{5,6}},   // k=4
        {{0,5},{1,3},{2,7},{4,6}},   // k=5
        {{0,6},{1,7},{2,3},{4,5}},   // k=6
        {{0,7},{1,6},{2,5},{3,4}},   // k=7
    };
    #pragma unroll
    for (int kk = 0; kk < 7; ++kk) {
        float4 a = make_float4(0.f, 0.f, 0.f, 0.f);
        #pragma unroll
        for (int t2 = 0; t2 < 4; ++t2) {
            const int i = P[kk][t2][0], j = P[kk][t2][1];
            const float cc = COEF(vf, i, j);
            a.x += cc * xv[i].x * xv[j].x;
            a.y += cc * xv[i].y * xv[j].y;
            a.z += cc * xv[i].z * xv[j].z;
            a.w += cc * xv[i].w * xv[j].w;
        }
        float* p = out + base + (kk + 1) * DDIM;
        __builtin_nontemporal_store(a.x, p + 0);
        __builtin_nontemporal_store(a.y, p + 1);
        __builtin_nontemporal_store(a.z, p + 2);
        __builtin_nontemporal_store(a.w, p + 3);
    }
}

__global__ __launch_bounds__(256) void geoprod_kernel(
    const float* __restrict__ x, const float* __restrict__ w,
    float* __restrict__ out, int n_threads)
{
    const int tid = threadIdx.x;
    const int lane = tid & 63;

    // ---- per-wave coefficient build: no LDS, no barriers ----
    const int order[8] = {0, 1, 2, 4, 3, 5, 6, 7};
    const int li = lane >> 3, lj = lane & 7;
    const int a = order[li], b = order[lj];
    int s = 0, t = a >> 1;
    while (t) { s += __popc(t & b); t >>= 1; }
    const float sig = 1.0f / (1.0f + __expf(-w[lane]));
    float v = (s & 1) ? -sig : sig;
    if (li == lj) v *= 0.5f;                     // diagonal folds with itself
    const float vf = v + __shfl(v, lj * 8 + li); // + partner term (j,i)

    // ---- 2-deep software pipeline: issue B's loads before A's compute ----
    const int stride = gridDim.x * 256;
    const int gid0 = blockIdx.x * 256 + tid;
    const int gid1 = gid0 + stride;

    float4 xvA[8], xvB[8];
    const bool has0 = gid0 < n_threads;
    const bool has1 = gid1 < n_threads;

    const int base0 = (gid0 >> 6) * (8 * DDIM) + (gid0 & 63) * 4;
    const int base1 = (gid1 >> 6) * (8 * DDIM) + (gid1 & 63) * 4;

    if (has0) load_x(x, base0, xvA);
    if (has1) load_x(x, base1, xvB);   // in flight while A computes/stores

    if (has0) compute_store(xvA, vf, out, base0);
    if (has1) compute_store(xvB, vf, out, base1);
}

extern "C" void kernel_launch(void* const* d_in, const int* in_sizes, int n_in,
                              void* d_out, int out_size, void* d_ws, size_t ws_size,
                              hipStream_t stream) {
    const float* x = (const float*)d_in[0];
    const float* w = (const float*)d_in[1];
    float* out = (float*)d_out;

    const int total = in_sizes[0];            // B*T*NB*D elements
    const int n_threads = total / 32;         // each thread-iter: 8 blades x 4 elems
    const int blocks = (n_threads + 2 * 256 - 1) / (2 * 256);  // 2 iters/thread

    geoprod_kernel<<<blocks, 256, 0, stream>>>(x, w, out, n_threads);
}